// Round 4
// baseline (152.149 us; speedup 1.0000x reference)
//
#include <hip/hip_runtime.h>

// VQ-VAE vector quantizer. N=131072 rows (32*64*64), D=64, K=512.
// X: NCHW f32 (32,64,64,64); W: (512,64) f32.
// out: [0]=loss, [1..8388609)=quantized NCHW, [8388609]=perplexity,
//      [8388610..)=one-hot encodings [131072][512].
#define BHW 262144
#define OUT_Q_OFF 1
#define OUT_P_OFF 8388609
#define OUT_E_OFF 8388610

// ws layout (4-byte words):
// [0] loss accum (f32) | [1..513) counts (u32) | [513..1025) wsq (f32)
// [1032..17416) pre-swizzled bf16 codebook B-fragments [tn=32][j=2][lane=64] x 8 bf16

typedef __attribute__((ext_vector_type(8))) short short8;
typedef __attribute__((ext_vector_type(4))) float f32x4;
typedef __attribute__((ext_vector_type(2))) float f32x2;

__device__ __forceinline__ unsigned short f2bf(float f) {
    union { float f; unsigned u; } c; c.f = f;
    unsigned r = (c.u + 0x7FFFu + ((c.u >> 16) & 1u)) >> 16;  // RNE
    return (unsigned short)r;
}

__global__ __launch_bounds__(512) void vq_init(const float* __restrict__ W, float* __restrict__ ws) {
    const int tid = blockIdx.x * 512 + threadIdx.x;
    if (tid < 512) {
        const float4* W4 = (const float4*)W;
        float s = 0.f;
#pragma unroll
        for (int i = 0; i < 16; ++i) {
            float4 v = W4[tid * 16 + i];
            s = fmaf(v.x, v.x, s); s = fmaf(v.y, v.y, s);
            s = fmaf(v.z, v.z, s); s = fmaf(v.w, v.w, s);
        }
        ws[513 + tid] = s;
    } else {
        // B-fragment pre-swizzle: chunk c -> (tn, j, lane)
        const int c  = tid - 512;            // 0..4095
        const int l  = c & 63;
        const int j  = (c >> 6) & 1;
        const int tn = c >> 7;
        const int n  = tn * 16 + (l & 15);
        const int k0 = j * 32 + ((l >> 4) & 3) * 8;
        const float* src = W + n * 64 + k0;
        unsigned h0 = f2bf(src[0]) | ((unsigned)f2bf(src[1]) << 16);
        unsigned h1 = f2bf(src[2]) | ((unsigned)f2bf(src[3]) << 16);
        unsigned h2 = f2bf(src[4]) | ((unsigned)f2bf(src[5]) << 16);
        unsigned h3 = f2bf(src[6]) | ((unsigned)f2bf(src[7]) << 16);
        uint4* dst = (uint4*)(ws + 1032);
        dst[c] = make_uint4(h0, h1, h2, h3);
    }
}

__global__ __launch_bounds__(256, 4) void vq_main(const float* __restrict__ X,
                                                  const float* __restrict__ W,
                                                  float* __restrict__ out,
                                                  float* __restrict__ ws) {
    const int t    = threadIdx.x;
    const int l    = t & 63;
    const int wv   = t >> 6;
    const int nlow = l & 15;
    const int kg   = l >> 4;
    const int rowbase = blockIdx.x * 64;     // 64 rows per block, shared (b,h)
    const int b = rowbase >> 12;
    const int h = (rowbase >> 6) & 63;

    __shared__ float partS[4][64];
    __shared__ int   partK[4][64];
    __shared__ int   best_lds[64];
    __shared__ float red[4];

    // ---- A fragments for ALL 4 row-groups (rows g*16+nlow, dims via (kg,slot)) ----
    // keep f32 x only for this wave's own row-group (epilogue)
    short8 a[4][2];
    float  xf[16];
    const float* xbase = X + (size_t)b * BHW + (size_t)h * 64 + nlow;
#pragma unroll
    for (int g = 0; g < 4; ++g) {
        float tmp[16];
        const float* xr = xbase + g * 16;
#pragma unroll
        for (int e = 0; e < 8; ++e) tmp[e]     = xr[(size_t)(kg * 8 + e) * 4096];
#pragma unroll
        for (int e = 0; e < 8; ++e) tmp[8 + e] = xr[(size_t)(32 + kg * 8 + e) * 4096];
        short8 c0, c1;
#pragma unroll
        for (int e = 0; e < 8; ++e) { c0[e] = (short)f2bf(tmp[e]); c1[e] = (short)f2bf(tmp[8 + e]); }
        a[g][0] = c0; a[g][1] = c1;
        if (g == wv) {
#pragma unroll
            for (int e = 0; e < 16; ++e) xf[e] = tmp[e];
        }
    }

    // ---- scores: this wave scans codes [wv*128, wv*128+128) for all 64 rows ----
    const short8* __restrict__ B8  = (const short8*)(ws + 1032);
    const float*  __restrict__ wsq = ws + 513;
    float bS[4][4];
    int   bK[4][4];
#pragma unroll
    for (int g = 0; g < 4; ++g)
#pragma unroll
        for (int r = 0; r < 4; ++r) { bS[g][r] = 3.4e38f; bK[g][r] = 0; }

#pragma unroll 2
    for (int tn = 0; tn < 8; ++tn) {
        const int tni = wv * 8 + tn;
        short8 f0 = B8[tni * 128 + l];
        short8 f1 = B8[tni * 128 + 64 + l];
        const int   n  = tni * 16 + nlow;
        const float wq = wsq[n];
#pragma unroll
        for (int g = 0; g < 4; ++g) {
            f32x4 acc = {0.f, 0.f, 0.f, 0.f};
            acc = __builtin_amdgcn_mfma_f32_16x16x32_bf16(a[g][0], f0, acc, 0, 0, 0);
            acc = __builtin_amdgcn_mfma_f32_16x16x32_bf16(a[g][1], f1, acc, 0, 0, 0);
#pragma unroll
            for (int r = 0; r < 4; ++r) {
                float s = fmaf(-2.f, acc[r], wq);
                if (s < bS[g][r]) { bS[g][r] = s; bK[g][r] = n; }
            }
        }
    }

    // min-reduce across the 16 n-lanes (within kg group); lowest-k tiebreak
#pragma unroll
    for (int g = 0; g < 4; ++g)
#pragma unroll
        for (int r = 0; r < 4; ++r) {
            float s = bS[g][r]; int k = bK[g][r];
#pragma unroll
            for (int mask = 1; mask <= 8; mask <<= 1) {
                float os = __shfl_xor(s, mask);
                int   ok = __shfl_xor(k, mask);
                if (os < s || (os == s && ok < k)) { s = os; k = ok; }
            }
            if (nlow == 0) {      // D row m_local = kg*4 + r  (m89-verified layout)
                partS[wv][g * 16 + kg * 4 + r] = s;
                partK[wv][g * 16 + kg * 4 + r] = k;
            }
        }
    __syncthreads();

    // ---- combine wave partials (k-ranges ordered by wave -> lexicographic min) ----
    if (t < 64) {
        float s = partS[0][t]; int k = partK[0][t];
#pragma unroll
        for (int v = 1; v < 4; ++v) {
            float os = partS[v][t]; int ok = partK[v][t];
            if (os < s || (os == s && ok < k)) { s = os; k = ok; }
        }
        best_lds[t] = k;
        atomicAdd((unsigned*)ws + 1 + k, 1u);
    }
    __syncthreads();

    // ---- epilogue: quantized_st + loss, fully register-resident x ----
    const int w_  = wv * 16 + nlow;          // this wave's row
    const int bk  = best_lds[w_];            // broadcast across kg lanes
    const float4* W4 = (const float4*)W;
    float4 q0 = W4[bk * 16 + kg * 2];
    float4 q1 = W4[bk * 16 + kg * 2 + 1];
    float4 q2 = W4[bk * 16 + 8 + kg * 2];
    float4 q3 = W4[bk * 16 + 8 + kg * 2 + 1];
    float qv[16] = {q0.x, q0.y, q0.z, q0.w, q1.x, q1.y, q1.z, q1.w,
                    q2.x, q2.y, q2.z, q2.w, q3.x, q3.y, q3.z, q3.w};
    float lsum = 0.f;
    float* op = out + OUT_Q_OFF + (size_t)b * BHW + (size_t)h * 64 + w_;
#pragma unroll
    for (int e = 0; e < 8; ++e) {
        float d0 = qv[e] - xf[e];
        lsum = fmaf(d0, d0, lsum);
        __builtin_nontemporal_store(xf[e] + d0, op + (size_t)(kg * 8 + e) * 4096);
        float d1 = qv[8 + e] - xf[8 + e];
        lsum = fmaf(d1, d1, lsum);
        __builtin_nontemporal_store(xf[8 + e] + d1, op + (size_t)(32 + kg * 8 + e) * 4096);
    }

    // ---- one-hot encodings (coalesced f32x2 NT stores; region 8B-aligned) ----
    f32x2* enc2 = (f32x2*)(out + OUT_E_OFF);
    const size_t ebase = ((size_t)rowbase) << 8;
#pragma unroll 1
    for (int i = 0; i < 64; ++i) {
        int bki = best_lds[i];
        f32x2 v;
        v.x = (bki == 2 * t)     ? 1.f : 0.f;
        v.y = (bki == 2 * t + 1) ? 1.f : 0.f;
        __builtin_nontemporal_store(v, enc2 + ebase + ((size_t)i << 8) + t);
    }

    // ---- loss reduction ----
#pragma unroll
    for (int off = 32; off >= 1; off >>= 1) lsum += __shfl_down(lsum, off);
    if (l == 0) red[wv] = lsum;
    __syncthreads();
    if (t == 0) atomicAdd(ws, red[0] + red[1] + red[2] + red[3]);
}

__global__ __launch_bounds__(512) void vq_fin(const float* __restrict__ ws, float* __restrict__ out) {
    __shared__ float red[8];
    const int t = threadIdx.x;
    const unsigned* counts = (const unsigned*)ws + 1;
    float p = (float)counts[t] * (1.0f / 131072.0f);
    float s = p * logf(p + 1e-10f);
#pragma unroll
    for (int off = 32; off >= 1; off >>= 1) s += __shfl_down(s, off);
    if ((t & 63) == 0) red[t >> 6] = s;
    __syncthreads();
    if (t == 0) {
        float tot = 0.f;
#pragma unroll
        for (int i = 0; i < 8; ++i) tot += red[i];
        out[OUT_P_OFF] = expf(-tot);
        out[0] = ws[0] * (1.25f / 8388608.0f);
    }
}

extern "C" void kernel_launch(void* const* d_in, const int* in_sizes, int n_in,
                              void* d_out, int out_size, void* d_ws, size_t ws_size,
                              hipStream_t stream) {
    const float* X = (const float*)d_in[0];
    const float* W = (const float*)d_in[1];
    float* out = (float*)d_out;
    float* ws  = (float*)d_ws;

    (void)hipMemsetAsync(d_ws, 0, 513 * sizeof(float), stream);   // loss + counts
    vq_init<<<9, 512, 0, stream>>>(W, ws);
    vq_main<<<2048, 256, 0, stream>>>(X, W, out, ws);
    vq_fin<<<1, 512, 0, stream>>>(ws, out);
}

// Round 5
// 116.541 us; speedup vs baseline: 1.3055x; 1.3055x over previous
//
#include <hip/hip_runtime.h>

// VQ-VAE vector quantizer. N=131072 rows (32*64*64), D=64, K=512.
// X: NCHW f32 (32,64,64,64); W: (512,64) f32.
// out: [0]=loss, [1..8388609)=quantized NCHW, [8388609]=perplexity,
//      [8388610..)=one-hot encodings [131072][512].
#define BHW 262144
#define OUT_Q_OFF 1
#define OUT_P_OFF 8388609
#define OUT_E_OFF 8388610

// ws layout (4-byte words):
// [0..256)     loss partial slots (f32)        -- memset 0
// [256..768)   counts (u32)                    -- memset 0
// [768..1280)  wsq = ||e_k||^2 (f32)
// [1280..17664) bf16 codebook B-fragments, PRE-SCALED by -2: [tn=32][j=2][lane=64] x 8 bf16

typedef __attribute__((ext_vector_type(8))) short short8;
typedef __attribute__((ext_vector_type(4))) float f32x4;
typedef __attribute__((ext_vector_type(2))) float f32x2;

__device__ __forceinline__ unsigned short f2bf(float f) {
    union { float f; unsigned u; } c; c.f = f;
    unsigned r = (c.u + 0x7FFFu + ((c.u >> 16) & 1u)) >> 16;  // RNE
    return (unsigned short)r;
}

__global__ __launch_bounds__(512) void vq_init(const float* __restrict__ W, float* __restrict__ ws) {
    const int tid = blockIdx.x * 512 + threadIdx.x;
    if (tid < 512) {
        const float4* W4 = (const float4*)W;
        float s = 0.f;
#pragma unroll
        for (int i = 0; i < 16; ++i) {
            float4 v = W4[tid * 16 + i];
            s = fmaf(v.x, v.x, s); s = fmaf(v.y, v.y, s);
            s = fmaf(v.z, v.z, s); s = fmaf(v.w, v.w, s);
        }
        ws[768 + tid] = s;
    } else {
        // B-fragment pre-swizzle (scaled by -2): chunk c -> (tn, j, lane)
        const int c  = tid - 512;            // 0..4095
        const int l  = c & 63;
        const int j  = (c >> 6) & 1;
        const int tn = c >> 7;
        const int n  = tn * 16 + (l & 15);
        const int k0 = j * 32 + ((l >> 4) & 3) * 8;
        const float* src = W + n * 64 + k0;
        unsigned h0 = f2bf(-2.f * src[0]) | ((unsigned)f2bf(-2.f * src[1]) << 16);
        unsigned h1 = f2bf(-2.f * src[2]) | ((unsigned)f2bf(-2.f * src[3]) << 16);
        unsigned h2 = f2bf(-2.f * src[4]) | ((unsigned)f2bf(-2.f * src[5]) << 16);
        unsigned h3 = f2bf(-2.f * src[6]) | ((unsigned)f2bf(-2.f * src[7]) << 16);
        uint4* dst = (uint4*)(ws + 1280);
        dst[c] = make_uint4(h0, h1, h2, h3);
    }
}

// One wave per block, 16 rows per wave. No LDS, no barriers.
__global__ __launch_bounds__(64) void vq_main(const float* __restrict__ X,
                                              const float* __restrict__ W,
                                              float* __restrict__ out,
                                              float* __restrict__ ws) {
    const int l    = threadIdx.x;        // 0..63
    const int nlow = l & 15;
    const int kg   = l >> 4;
    const int rowbase = blockIdx.x * 16; // 16 consecutive rows, same (b,h)
    const int b  = rowbase >> 12;
    const int h  = (rowbase >> 6) & 63;
    const int w0 = rowbase & 63;

    // ---- this lane's x row (A-frag row = nlow), dims (kg,e); kept for epilogue ----
    const float* xr = X + (size_t)b * BHW + (size_t)h * 64 + (w0 + nlow);
    float xf[16];
#pragma unroll
    for (int e = 0; e < 8; ++e) xf[e]     = xr[(size_t)(kg * 8 + e) * 4096];
#pragma unroll
    for (int e = 0; e < 8; ++e) xf[8 + e] = xr[(size_t)(32 + kg * 8 + e) * 4096];
    short8 a0, a1;
#pragma unroll
    for (int e = 0; e < 8; ++e) { a0[e] = (short)f2bf(xf[e]); a1[e] = (short)f2bf(xf[8 + e]); }

    // ---- scan all 512 codes: score = wsq (C-init) + (-2e)·x via MFMA ----
    const short8* __restrict__ B8  = (const short8*)(ws + 1280);
    const float*  __restrict__ wsq = ws + 768;
    float bS[4]; int bK[4];
#pragma unroll
    for (int r = 0; r < 4; ++r) { bS[r] = 3.4e38f; bK[r] = 0; }

#pragma unroll 2
    for (int tn = 0; tn < 32; ++tn) {
        short8 f0 = B8[tn * 128 + l];
        short8 f1 = B8[tn * 128 + 64 + l];
        const float wq = wsq[tn * 16 + nlow];
        f32x4 acc = {wq, wq, wq, wq};
        acc = __builtin_amdgcn_mfma_f32_16x16x32_bf16(a0, f0, acc, 0, 0, 0);
        acc = __builtin_amdgcn_mfma_f32_16x16x32_bf16(a1, f1, acc, 0, 0, 0);
        const int n = tn * 16 + nlow;
#pragma unroll
        for (int r = 0; r < 4; ++r) {
            if (acc[r] < bS[r]) { bS[r] = acc[r]; bK[r] = n; }
        }
    }
    // butterfly min-reduce over the 16 col-lanes of each kg group (lowest-k tiebreak);
    // afterwards ALL lanes in the group hold row m=kg*4+r's argmin
#pragma unroll
    for (int r = 0; r < 4; ++r) {
#pragma unroll
        for (int mask = 1; mask <= 8; mask <<= 1) {
            float os = __shfl_xor(bS[r], mask);
            int   ok = __shfl_xor(bK[r], mask);
            if (os < bS[r] || (os == bS[r] && ok < bK[r])) { bS[r] = os; bK[r] = ok; }
        }
    }

    // ---- broadcast per-row bests; write one-hot encodings inline ----
    int rowBk = 0;   // best for this lane's own row (nlow)
    int myBk  = 0;   // best for row l (lanes 0..15, histogram)
    f32x2* encB = (f32x2*)(out + OUT_E_OFF);
    const size_t Rbase = (size_t)rowbase;
#pragma unroll
    for (int m = 0; m < 16; ++m) {
        int bkm = __shfl(bK[m & 3], (m >> 2) * 16);
        if (nlow == m) rowBk = bkm;
        if (l == m)    myBk = bkm;
        f32x2* erow = encB + (Rbase + m) * 256;
#pragma unroll
        for (int c = 0; c < 4; ++c) {
            int p = c * 64 + l;
            f32x2 v;
            v.x = (bkm == 2 * p)     ? 1.f : 0.f;
            v.y = (bkm == 2 * p + 1) ? 1.f : 0.f;
            erow[p] = v;
        }
    }
    if (l < 16) atomicAdd((unsigned*)ws + 256 + myBk, 1u);

    // ---- quantized_st + loss partials (x register-resident) ----
    const float4* W4 = (const float4*)W;
    float4 q0 = W4[rowBk * 16 + kg * 2];
    float4 q1 = W4[rowBk * 16 + kg * 2 + 1];
    float4 q2 = W4[rowBk * 16 + 8 + kg * 2];
    float4 q3 = W4[rowBk * 16 + 8 + kg * 2 + 1];
    float qv[16] = {q0.x, q0.y, q0.z, q0.w, q1.x, q1.y, q1.z, q1.w,
                    q2.x, q2.y, q2.z, q2.w, q3.x, q3.y, q3.z, q3.w};
    float lsum = 0.f;
    float* op = out + OUT_Q_OFF + (size_t)b * BHW + (size_t)h * 64 + (w0 + nlow);
#pragma unroll
    for (int e = 0; e < 8; ++e) {
        float d0 = qv[e] - xf[e];
        lsum = fmaf(d0, d0, lsum);
        op[(size_t)(kg * 8 + e) * 4096] = xf[e] + d0;
        float d1 = qv[8 + e] - xf[8 + e];
        lsum = fmaf(d1, d1, lsum);
        op[(size_t)(32 + kg * 8 + e) * 4096] = xf[8 + e] + d1;
    }

    // ---- loss wave-reduce; spread atomics over 256 slots ----
#pragma unroll
    for (int off = 32; off >= 1; off >>= 1) lsum += __shfl_down(lsum, off);
    if (l == 0) atomicAdd(ws + (blockIdx.x & 255), lsum);
}

__global__ __launch_bounds__(512) void vq_fin(const float* __restrict__ ws, float* __restrict__ out) {
    __shared__ float redP[8], redL[8];
    const int t = threadIdx.x;
    const unsigned* counts = (const unsigned*)ws + 256;
    float p = (float)counts[t] * (1.0f / 131072.0f);
    float s = p * logf(p + 1e-10f);
    float lp = (t < 256) ? ws[t] : 0.f;
#pragma unroll
    for (int off = 32; off >= 1; off >>= 1) {
        s  += __shfl_down(s, off);
        lp += __shfl_down(lp, off);
    }
    if ((t & 63) == 0) { redP[t >> 6] = s; redL[t >> 6] = lp; }
    __syncthreads();
    if (t == 0) {
        float tp = 0.f, tl = 0.f;
#pragma unroll
        for (int i = 0; i < 8; ++i) { tp += redP[i]; tl += redL[i]; }
        out[OUT_P_OFF] = expf(-tp);
        out[0] = tl * (1.25f / 8388608.0f);
    }
}

extern "C" void kernel_launch(void* const* d_in, const int* in_sizes, int n_in,
                              void* d_out, int out_size, void* d_ws, size_t ws_size,
                              hipStream_t stream) {
    const float* X = (const float*)d_in[0];
    const float* W = (const float*)d_in[1];
    float* out = (float*)d_out;
    float* ws  = (float*)d_ws;

    (void)hipMemsetAsync(d_ws, 0, 768 * sizeof(float), stream);   // loss slots + counts
    vq_init<<<9, 512, 0, stream>>>(W, ws);
    vq_main<<<8192, 64, 0, stream>>>(X, W, out, ws);
    vq_fin<<<1, 512, 0, stream>>>(ws, out);
}